// Round 1
// baseline (3848.682 us; speedup 1.0000x reference)
//
#include <hip/hip_runtime.h>
#include <hip/hip_bf16.h>

#define NROWS 200000
#define HSZ 256
#define KTOT 1280          // 256 (x) + 4*256 (h_cat)
#define BM 128
#define BN 64              // d-columns per block
#define BK 64
#define NCH 3              // u, o, h_inner
#define MTILES ((NROWS + BM - 1) / BM)

typedef __attribute__((ext_vector_type(4))) float f32x4;
typedef __attribute__((ext_vector_type(8))) short bf16x8;

__device__ __forceinline__ void gload_lds16(const void* g, void* l) {
  __builtin_amdgcn_global_load_lds(
      (const __attribute__((address_space(1))) unsigned int*)g,
      (__attribute__((address_space(3))) unsigned int*)l, 16, 0, 0);
}

// Build combined bf16 weight matrix Wb[3*256][1280]:
//  row r = c*256 + d
//  c=0 (u):  k<256 -> W_ruo[256+d][k],  k>=256 -> U_ruo[256+d][k-256]
//  c=1 (o):  k<256 -> W_ruo[512+d][k],  k>=256 -> U_ruo[512+d][k-256]
//  c=2 (hi): k<256 -> 0,                k>=256 -> U_u2[d][k-256]
__global__ void build_wb(const float* __restrict__ W_ruo,
                         const float* __restrict__ U_ruo,
                         const float* __restrict__ U_u2,
                         __hip_bfloat16* __restrict__ Wb) {
  int idx = blockIdx.x * blockDim.x + threadIdx.x;
  if (idx >= NCH * HSZ * KTOT) return;
  int k  = idx % KTOT;
  int rd = idx / KTOT;
  int c  = rd >> 8;
  int d  = rd & 255;
  float v;
  if (c == 2) {
    v = (k < 256) ? 0.0f : U_u2[d * 1024 + (k - 256)];
  } else {
    int row = (c + 1) * 256 + d;
    v = (k < 256) ? W_ruo[row * 256 + k] : U_ruo[row * 1024 + (k - 256)];
  }
  Wb[idx] = __float2bfloat16(v);
}

__global__ __launch_bounds__(256) void fused_gemm(
    const float* __restrict__ x, const float* __restrict__ h_prev,
    const float* __restrict__ b_ruo, const __hip_bfloat16* __restrict__ Wb,
    const int* __restrict__ child_idx, const int* __restrict__ child_mask,
    float* __restrict__ out) {
  __shared__ char ldsA[BM * BK * 2];        // 16 KB, XOR-swizzled rows of 128 B
  __shared__ char ldsB[NCH * BN * BK * 2];  // 24 KB, same swizzle

  const int tid  = threadIdx.x;
  const int wid  = tid >> 6;
  const int lane = tid & 63;
  const int wr   = wid >> 1;          // wave row-half (64 rows)
  const int wc   = wid & 1;           // wave col-half (32 d-cols)
  const int m0   = blockIdx.y * BM;
  const int d0   = blockIdx.x * BN;

  f32x4 acc[NCH][4][2];
#pragma unroll
  for (int c = 0; c < NCH; ++c)
#pragma unroll
    for (int mr = 0; mr < 4; ++mr)
#pragma unroll
      for (int nc = 0; nc < 2; ++nc) acc[c][mr][nc] = (f32x4){0.f, 0.f, 0.f, 0.f};

  const int sr = tid >> 4;   // staging row-in-pass 0..15
  const int sc = tid & 15;   // staging col group (4 f32)

  for (int ks = 0; ks < KTOT / BK; ++ks) {
    const int k0     = ks * BK;
    const int region = k0 >> 8;       // 0 -> x, 1..4 -> child region-1
    const int kin    = k0 & 255;
    __syncthreads();
    // ---- stage A: gather + f32->bf16 + swizzled ds_write ----
#pragma unroll
    for (int pass = 0; pass < 8; ++pass) {
      const int r   = pass * 16 + sr;
      const long gi = (long)m0 + r;
      f32x4 v = (f32x4){0.f, 0.f, 0.f, 0.f};
      if (gi < NROWS) {
        if (region == 0) {
          v = *(const f32x4*)(x + gi * HSZ + kin + sc * 4);
        } else {
          const int j = region - 1;
          if (child_mask[gi * 4 + j]) {
            const long ci = child_idx[gi * 4 + j];
            v = *(const f32x4*)(h_prev + ci * HSZ + kin + sc * 4);
          }
        }
      }
      union { __hip_bfloat16 h[4]; unsigned long long u; } cv;
      cv.h[0] = __float2bfloat16(v.x);
      cv.h[1] = __float2bfloat16(v.y);
      cv.h[2] = __float2bfloat16(v.z);
      cv.h[3] = __float2bfloat16(v.w);
      const int off = r * 128 + ((sc * 8) ^ ((r & 7) << 4));
      *(unsigned long long*)(ldsA + off) = cv.u;
    }
    // ---- stage B: global_load_lds, linear LDS dest + inverse-swizzled source ----
#pragma unroll
    for (int it = 0; it < 6; ++it) {
      const int v    = it * 256 + tid;              // 0..1535 (16B chunks)
      const int brow = v >> 3;                      // 0..191
      const int cb   = ((v & 7) * 16) ^ ((brow & 7) << 4);
      const int wrow = (brow >> 6) * HSZ + d0 + (brow & 63);
      const __hip_bfloat16* src = Wb + (long)wrow * KTOT + k0 + (cb >> 1);
      gload_lds16(src, ldsB + (it * 256 + (tid & ~63)) * 16);
    }
    __syncthreads();
    // ---- MFMA: 48 per wave per K-step ----
    bf16x8 af[4][2];
#pragma unroll
    for (int mr = 0; mr < 4; ++mr)
#pragma unroll
      for (int kf = 0; kf < 2; ++kf) {
        const int row = wr * 64 + mr * 16 + (lane & 15);
        const int kb  = (kf * 64 + ((lane >> 4) << 4)) ^ ((row & 7) << 4);
        af[mr][kf] = *(const bf16x8*)(ldsA + row * 128 + kb);
      }
#pragma unroll
    for (int c = 0; c < NCH; ++c)
#pragma unroll
      for (int nc = 0; nc < 2; ++nc)
#pragma unroll
        for (int kf = 0; kf < 2; ++kf) {
          const int br = c * 64 + wc * 32 + nc * 16 + (lane & 15);
          const int kb = (kf * 64 + ((lane >> 4) << 4)) ^ ((br & 7) << 4);
          const bf16x8 bf = *(const bf16x8*)(ldsB + br * 128 + kb);
#pragma unroll
          for (int mr = 0; mr < 4; ++mr)
            acc[c][mr][nc] = __builtin_amdgcn_mfma_f32_16x16x32_bf16(
                af[mr][kf], bf, acc[c][mr][nc], 0, 0, 0);
        }
  }
  // ---- epilogue: u=sigmoid, o=tanh, h = o*u + (1-u)*h_inner ----
  const int lr = lane >> 4;
  const int lc = lane & 15;
#pragma unroll
  for (int nc = 0; nc < 2; ++nc) {
    const int d  = d0 + wc * 32 + nc * 16 + lc;
    const float bu = b_ruo[HSZ + d];        // bias for u (cols 256..511)
    const float bo = b_ruo[2 * HSZ + d];    // bias for o (cols 512..767)
#pragma unroll
    for (int mr = 0; mr < 4; ++mr) {
#pragma unroll
      for (int reg = 0; reg < 4; ++reg) {
        const long gi = (long)m0 + wr * 64 + mr * 16 + lr * 4 + reg;
        if (gi < NROWS) {
          const float upre = acc[0][mr][nc][reg] + bu;
          const float opre = acc[1][mr][nc][reg] + bo;
          const float u  = 1.f / (1.f + __expf(-upre));
          const float e2 = __expf(-2.f * opre);
          const float o  = (1.f - e2) / (1.f + e2);
          out[gi * HSZ + d] = o * u + (1.f - u) * acc[2][mr][nc][reg];
        }
      }
    }
  }
}

extern "C" void kernel_launch(void* const* d_in, const int* in_sizes, int n_in,
                              void* d_out, int out_size, void* d_ws, size_t ws_size,
                              hipStream_t stream) {
  const float* x        = (const float*)d_in[0];
  const float* h_prev   = (const float*)d_in[1];
  const float* W_ruo    = (const float*)d_in[2];
  const float* U_ruo    = (const float*)d_in[3];
  const float* b_ruo    = (const float*)d_in[4];
  const float* U_u2     = (const float*)d_in[5];
  const int* child_idx  = (const int*)d_in[6];
  const int* child_mask = (const int*)d_in[7];
  float* out            = (float*)d_out;
  __hip_bfloat16* Wb    = (__hip_bfloat16*)d_ws;   // 3*256*1280*2 = 1.92 MB

  const int nWb = NCH * HSZ * KTOT;
  build_wb<<<(nWb + 255) / 256, 256, 0, stream>>>(W_ruo, U_ruo, U_u2, Wb);

  dim3 grid(HSZ / BN, MTILES);   // 4 x 1563
  fused_gemm<<<grid, 256, 0, stream>>>(x, h_prev, b_ruo, Wb, child_idx,
                                       child_mask, out);
}